// Round 11
// baseline (566.209 us; speedup 1.0000x reference)
//
#include <hip/hip_runtime.h>
#include <hip/hip_bf16.h>
#include <cstdint>
#include <cstddef>

#ifndef __has_builtin
#define __has_builtin(x) 0
#endif

#define DEVI __device__ __forceinline__

typedef __attribute__((ext_vector_type(8))) __bf16 bf16x8;
typedef __attribute__((ext_vector_type(4))) float float4v;
typedef __attribute__((ext_vector_type(16))) float float16v;
typedef __attribute__((ext_vector_type(4))) unsigned short ushort4v;
typedef __attribute__((ext_vector_type(4))) unsigned int uint4v;

constexpr int Bd = 4, Sd = 1024, Ld = 2048, Hd = 16, Dd = 64;

DEVI unsigned short f2bf(float x){
  union { float f; unsigned u; } v; v.f = x;
  unsigned r = v.u + 0x7fffu + ((v.u >> 16) & 1u);
  return (unsigned short)(r >> 16);
}

// Half-up pack two f32 -> u32 of 2 bf16 (lo | hi<<16). 3 VALU ops.
DEVI unsigned pack2(float lo, float hi){
  union { float f; unsigned u; } a, b; a.f = lo; b.f = hi;
  unsigned ra = a.u + 0x8000u;
  unsigned rb = b.u + 0x8000u;
#if __has_builtin(__builtin_amdgcn_perm)
  return __builtin_amdgcn_perm(rb, ra, 0x07060302u);  // D = [rb.hi16 | ra.hi16]
#else
  return (ra >> 16) | (rb & 0xffff0000u);
#endif
}

DEVI float fast_exp2(float x){
#if __has_builtin(__builtin_amdgcn_exp2f)
  return __builtin_amdgcn_exp2f(x);
#else
  return exp2f(x);
#endif
}

// v_permlane32_swap_b32 D,S: new_D=[D.lo|S.lo], new_S=[D.hi|S.hi] (lane halves).
DEVI void plane32_swap(unsigned &a, unsigned &b){
  asm("v_permlane32_swap_b32 %0, %1" : "+v"(a), "+v"(b));
}

DEVI void gload_lds16(const void* g, void* lds){
  __builtin_amdgcn_global_load_lds(
      (const __attribute__((address_space(1))) void*)g,
      (__attribute__((address_space(3))) void*)lds,
      16, 0, 0);
}

DEVI float4v mfma_bf16(bf16x8 a, bf16x8 b, float4v c){
  return __builtin_amdgcn_mfma_f32_16x16x32_bf16(a, b, c, 0, 0, 0);
}

DEVI float16v mfma32_bf16(bf16x8 a, bf16x8 b, float16v c){
  return __builtin_amdgcn_mfma_f32_32x32x16_bf16(a, b, c, 0, 0, 0);
}

// ---------------- prep kernels ----------------

__global__ void wcast_kernel(const float* __restrict__ Wk, const float* __restrict__ Wq,
                             const float* __restrict__ Wp,
                             unsigned short* __restrict__ Wkbf, unsigned short* __restrict__ Wqbf,
                             unsigned short* __restrict__ Wpbf, float ck){
  size_t i = ((size_t)blockIdx.x * 256 + threadIdx.x) * 4;
  float4v a = *(const float4v*)(Wk + i);
  float4v b = *(const float4v*)(Wq + i);
  float4v c = *(const float4v*)(Wp + i);
  ushort4v oa = { f2bf(a[0]*ck), f2bf(a[1]*ck), f2bf(a[2]*ck), f2bf(a[3]*ck) };
  ushort4v ob = { f2bf(b[0]), f2bf(b[1]), f2bf(b[2]), f2bf(b[3]) };
  ushort4v oc = { f2bf(c[0]), f2bf(c[1]), f2bf(c[2]), f2bf(c[3]) };
  *(ushort4v*)(Wkbf + i) = oa;
  *(ushort4v*)(Wqbf + i) = ob;
  *(ushort4v*)(Wpbf + i) = oc;
}

// x (B,S,L) f32 -> Xt (B,L,S) bf16. float4 loads, ushort4 stores.
__global__ void transpose_cast(const float* __restrict__ x, unsigned short* __restrict__ Xt){
  __shared__ float tile[32][33];
  const int b = blockIdx.z;
  const int l0 = blockIdx.x * 32;
  const int s0 = blockIdx.y * 32;
  const int t = threadIdx.x;           // 256 threads
  {
    const int r = t >> 3, c4 = (t & 7) * 4;   // s-row r, l-col group c4
    float4v v = *(const float4v*)(x + ((size_t)b*Sd + s0 + r)*Ld + l0 + c4);
    tile[r][c4+0] = v[0]; tile[r][c4+1] = v[1];
    tile[r][c4+2] = v[2]; tile[r][c4+3] = v[3];
  }
  __syncthreads();
  {
    const int l = t >> 3, g4 = (t & 7) * 4;   // l-row, s-col group
    ushort4v o = { f2bf(tile[g4+0][l]), f2bf(tile[g4+1][l]),
                   f2bf(tile[g4+2][l]), f2bf(tile[g4+3][l]) };
    *(ushort4v*)(Xt + ((size_t)b*Ld + l0 + l)*Sd + s0 + g4) = o;
  }
}

// ---------------- conv1x1 GEMM (128x128 tile, BK=32, dbuf, global_load_lds) ----------------
template<int OUT_MODE>
__global__ __launch_bounds__(256, 2)
void conv_gemm(const unsigned short* __restrict__ A,
               const unsigned short* __restrict__ Bt,
               const float* __restrict__ bias, float bscale,
               unsigned short* __restrict__ outT,
               float* __restrict__ outF)
{
  constexpr int BK = 32;
  constexpr int NKSTEP = Sd / BK;  // 32
  __shared__ __attribute__((aligned(16))) unsigned short Abuf[2][128*BK];
  __shared__ __attribute__((aligned(16))) unsigned short Bbuf[2][128*BK];

  const int b  = blockIdx.z;
  const int n0 = blockIdx.x * 128;
  const int m0 = blockIdx.y * 128;
  const int tid = threadIdx.x;
  const int w = tid >> 6, lane = tid & 63, lr = lane & 15, lg = lane >> 4;
  const int wm = (w >> 1) * 64, wn = (w & 1) * 64;

  const unsigned short* Abase = A + (size_t)m0 * Sd;
  const unsigned short* Bbase = Bt + ((size_t)b * Ld + n0) * Sd;

  auto stage = [&](int bf, int kt){
    #pragma unroll
    for (int p = 0; p < 2; ++p){
      int slot = p*256 + tid;
      int row = slot >> 2, c = slot & 3;
      int csrc = c ^ ((row >> 1) & 3);
      gload_lds16(Abase + (size_t)row * Sd + kt*BK + csrc*8,
                  (void*)(&Abuf[bf][(size_t)(p*256 + w*64) * 8]));
    }
    #pragma unroll
    for (int p = 0; p < 2; ++p){
      int slot = p*256 + tid;
      int row = slot >> 2, c = slot & 3;
      int csrc = c ^ ((row >> 1) & 3);
      gload_lds16(Bbase + (size_t)row * Sd + kt*BK + csrc*8,
                  (void*)(&Bbuf[bf][(size_t)(p*256 + w*64) * 8]));
    }
  };

  const int gsw = lg ^ ((lr >> 1) & 3);

  float4v acc[4][4];
  #pragma unroll
  for (int i = 0; i < 4; ++i)
    #pragma unroll
    for (int j = 0; j < 4; ++j)
      acc[i][j] = (float4v){0.f, 0.f, 0.f, 0.f};

  stage(0, 0);
  __syncthreads();
  int cur = 0;
  for (int kt = 0; kt < NKSTEP; ++kt){
    if (kt + 1 < NKSTEP) stage(cur ^ 1, kt + 1);
    bf16x8 af[4], bfv[4];
    #pragma unroll
    for (int i = 0; i < 4; ++i){
      int row = wm + i*16 + lr;
      af[i] = *(const bf16x8*)((const char*)&Abuf[cur][0] + (size_t)row*64 + gsw*16);
    }
    #pragma unroll
    for (int j = 0; j < 4; ++j){
      int row = wn + j*16 + lr;
      bfv[j] = *(const bf16x8*)((const char*)&Bbuf[cur][0] + (size_t)row*64 + gsw*16);
    }
    #pragma unroll
    for (int i = 0; i < 4; ++i)
      #pragma unroll
      for (int j = 0; j < 4; ++j)
        acc[i][j] = mfma_bf16(af[i], bfv[j], acc[i][j]);
    __syncthreads();
    cur ^= 1;
  }

  #pragma unroll
  for (int i = 0; i < 4; ++i){
    const int mb = m0 + wm + i*16 + lg*4;
    float4v bv = *(const float4v*)(bias + mb);
    #pragma unroll
    for (int j = 0; j < 4; ++j){
      const int n = n0 + wn + j*16 + lr;
      float4v v = acc[i][j];
      float o0 = v[0] + bscale*bv[0];
      float o1 = v[1] + bscale*bv[1];
      float o2 = v[2] + bscale*bv[2];
      float o3 = v[3] + bscale*bv[3];
      if (OUT_MODE == 0){
        ushort4v o = { f2bf(o0), f2bf(o1), f2bf(o2), f2bf(o3) };
        *(ushort4v*)(outT + ((size_t)b*Ld + n)*Sd + mb) = o;
      } else {
        outF[((size_t)b*Sd + mb + 0)*Ld + n] = o0;
        outF[((size_t)b*Sd + mb + 1)*Ld + n] = o1;
        outF[((size_t)b*Sd + mb + 2)*Ld + n] = o2;
        outF[((size_t)b*Sd + mb + 3)*Ld + n] = o3;
      }
    }
  }
}

// ---------------- fused K+Q conv: both GEMMs share the Xt B-operand ----------------
__global__ __launch_bounds__(256, 2)
void conv_gemm_kq(const unsigned short* __restrict__ Ak,
                  const unsigned short* __restrict__ Aq,
                  const unsigned short* __restrict__ Bt,
                  const float* __restrict__ bk, const float* __restrict__ bq,
                  float ck,
                  unsigned short* __restrict__ Kt,
                  unsigned short* __restrict__ Qt)
{
  constexpr int BK = 32;
  constexpr int NKSTEP = Sd / BK;  // 32
  __shared__ __attribute__((aligned(16))) unsigned short AbufK[2][128*BK];
  __shared__ __attribute__((aligned(16))) unsigned short AbufQ[2][128*BK];
  __shared__ __attribute__((aligned(16))) unsigned short Bbuf[2][128*BK];   // 48 KB total

  const int b  = blockIdx.z;
  const int n0 = blockIdx.x * 128;
  const int m0 = blockIdx.y * 128;
  const int tid = threadIdx.x;
  const int w = tid >> 6, lane = tid & 63, lr = lane & 15, lg = lane >> 4;
  const int wm = (w >> 1) * 64, wn = (w & 1) * 64;

  const unsigned short* AKbase = Ak + (size_t)m0 * Sd;
  const unsigned short* AQbase = Aq + (size_t)m0 * Sd;
  const unsigned short* Bbase  = Bt + ((size_t)b * Ld + n0) * Sd;

  auto stage = [&](int bf, int kt){
    #pragma unroll
    for (int p = 0; p < 2; ++p){
      int slot = p*256 + tid;
      int row = slot >> 2, c = slot & 3;
      int csrc = c ^ ((row >> 1) & 3);
      const size_t soff = (size_t)row * Sd + kt*BK + csrc*8;
      void* dk = (void*)(&AbufK[bf][(size_t)(p*256 + w*64) * 8]);
      void* dq = (void*)(&AbufQ[bf][(size_t)(p*256 + w*64) * 8]);
      void* db = (void*)(&Bbuf [bf][(size_t)(p*256 + w*64) * 8]);
      gload_lds16(AKbase + soff, dk);
      gload_lds16(AQbase + soff, dq);
      gload_lds16(Bbase  + soff, db);
    }
  };

  const int gsw = lg ^ ((lr >> 1) & 3);

  float4v acck[4][4], accq[4][4];
  #pragma unroll
  for (int i = 0; i < 4; ++i)
    #pragma unroll
    for (int j = 0; j < 4; ++j){
      acck[i][j] = (float4v){0.f, 0.f, 0.f, 0.f};
      accq[i][j] = (float4v){0.f, 0.f, 0.f, 0.f};
    }

  stage(0, 0);
  __syncthreads();
  int cur = 0;
  for (int kt = 0; kt < NKSTEP; ++kt){
    if (kt + 1 < NKSTEP) stage(cur ^ 1, kt + 1);
    bf16x8 afk[4], afq[4], bfv[4];
    #pragma unroll
    for (int i = 0; i < 4; ++i){
      int row = wm + i*16 + lr;
      afk[i] = *(const bf16x8*)((const char*)&AbufK[cur][0] + (size_t)row*64 + gsw*16);
      afq[i] = *(const bf16x8*)((const char*)&AbufQ[cur][0] + (size_t)row*64 + gsw*16);
    }
    #pragma unroll
    for (int j = 0; j < 4; ++j){
      int row = wn + j*16 + lr;
      bfv[j] = *(const bf16x8*)((const char*)&Bbuf[cur][0] + (size_t)row*64 + gsw*16);
    }
    #pragma unroll
    for (int i = 0; i < 4; ++i)
      #pragma unroll
      for (int j = 0; j < 4; ++j){
        acck[i][j] = mfma_bf16(afk[i], bfv[j], acck[i][j]);
        accq[i][j] = mfma_bf16(afq[i], bfv[j], accq[i][j]);
      }
    __syncthreads();
    cur ^= 1;
  }

  #pragma unroll
  for (int i = 0; i < 4; ++i){
    const int mb = m0 + wm + i*16 + lg*4;
    float4v bkv = *(const float4v*)(bk + mb);
    float4v bqv = *(const float4v*)(bq + mb);
    #pragma unroll
    for (int j = 0; j < 4; ++j){
      const int n = n0 + wn + j*16 + lr;
      float4v vk = acck[i][j];
      float4v vq = accq[i][j];
      ushort4v ok = { f2bf(vk[0] + ck*bkv[0]), f2bf(vk[1] + ck*bkv[1]),
                      f2bf(vk[2] + ck*bkv[2]), f2bf(vk[3] + ck*bkv[3]) };
      ushort4v oq = { f2bf(vq[0] + bqv[0]), f2bf(vq[1] + bqv[1]),
                      f2bf(vq[2] + bqv[2]), f2bf(vq[3] + bqv[3]) };
      *(ushort4v*)(Kt + ((size_t)b*Ld + n)*Sd + mb) = ok;
      *(ushort4v*)(Qt + ((size_t)b*Ld + n)*Sd + mb) = oq;
    }
  }
}

// ---------------- stats + fused vprime: invZ in LDS, Vp = bf16(x * invZ) ----------------
__global__ __launch_bounds__(256, 4)
void stats_kernel(const unsigned short* __restrict__ Kt,
                  const unsigned short* __restrict__ Qt,
                  const float* __restrict__ x,
                  unsigned short* __restrict__ Vp)
{
  __shared__ __attribute__((aligned(16))) unsigned short Qbuf[2][64*64];  // 16 KB
  __shared__ __attribute__((aligned(16))) float zbuf[256];                // 1 KB

  const int m = blockIdx.x;                    // 512 blocks
  const int xcd = m & 7, slot = m >> 3;        // 64 slots per XCD
  const int bh = xcd * 8 + (slot >> 3);        // 8 bh per XCD
  const int ib = slot & 7;
  const int b = bh >> 4, h = bh & 15;
  const int i0 = ib * 256;

  const int tid = threadIdx.x, w = tid >> 6, lane = tid & 63;
  const int l31 = lane & 31, lh = lane >> 5;
  const int iw0 = i0 + w * 64;

  bf16x8 kb[2][4];
  #pragma unroll
  for (int is = 0; is < 2; ++is)
    #pragma unroll
    for (int ks = 0; ks < 4; ++ks)
      kb[is][ks] = *(const bf16x8*)(Kt + ((size_t)b*Ld + iw0 + is*32 + l31)*Sd + h*64 + ks*16 + lh*8);

  const size_t qbase = (size_t)b*Ld*Sd + (size_t)h*64;
  auto stage = [&](int bf, int jt){
    const int j0 = jt * 64;
    #pragma unroll
    for (int p = 0; p < 2; ++p){
      const int slot2 = p*256 + tid;
      const int row = slot2 >> 3;
      const int gsrc = (slot2 & 7) ^ (row & 7);
      gload_lds16(Qt + qbase + (size_t)(j0 + row)*Sd + gsrc*8,
                  (void*)(&Qbuf[bf][(size_t)slot2 * 8]));
    }
  };

  float z[2] = {0.f, 0.f};
  stage(0, 0);
  __syncthreads();
  int cur = 0;
  for (int jt = 0; jt < 32; ++jt){
    if (jt + 1 < 32) stage(cur ^ 1, jt + 1);
    #pragma unroll
    for (int js = 0; js < 2; ++js){
      bf16x8 qf[4];
      #pragma unroll
      for (int ks = 0; ks < 4; ++ks){
        const int row = js*32 + l31;
        const int g = (2*ks + lh) ^ (l31 & 7);
        qf[ks] = *(const bf16x8*)((const char*)&Qbuf[cur][0] + (size_t)row*128 + g*16);
      }
      #pragma unroll
      for (int is = 0; is < 2; ++is){
        float16v sacc;
        #pragma unroll
        for (int r = 0; r < 16; ++r) sacc[r] = 0.f;
        __builtin_amdgcn_s_setprio(1);
        #pragma unroll
        for (int ks = 0; ks < 4; ++ks)
          sacc = mfma32_bf16(qf[ks], kb[is][ks], sacc);   // D[row=j][col=i]
        __builtin_amdgcn_s_setprio(0);
        #pragma unroll
        for (int r = 0; r < 16; ++r) z[is] += fast_exp2(sacc[r]);
      }
    }
    __syncthreads();
    cur ^= 1;
  }

  // invZ for this block's 256 i -> LDS
  #pragma unroll
  for (int is = 0; is < 2; ++is){
    float zv = z[is] + __shfl_xor(z[is], 32, 64);   // combine lh halves (disjoint j)
    if (lh == 0)
      zbuf[w*64 + is*32 + l31] = 1.0f / zv;
  }
  __syncthreads();

  // fused vprime: Vp[b][h*64+d][i0..i0+255] = bf16(x * invZ), 16 float4 per thread
  #pragma unroll
  for (int p = 0; p < 16; ++p){
    const int e = p*256 + tid;          // 4096 float4 groups
    const int d = e >> 6;               // 0..63
    const int c4 = (e & 63) * 4;        // i offset 0..252
    const size_t off = ((size_t)b*Sd + h*64 + d)*Ld + i0 + c4;
    float4v xv = *(const float4v*)(x + off);
    float4v zv = *(const float4v*)(&zbuf[c4]);
    ushort4v o = { f2bf(xv[0]*zv[0]), f2bf(xv[1]*zv[1]),
                   f2bf(xv[2]*zv[2]), f2bf(xv[3]*zv[3]) };
    *(ushort4v*)(Vp + off) = o;
  }
}

// ---------------- PV pass v10: K 3-pair-slot LDS, V direct-global, barrier per 2 tiles ----
// AOt[b][j][c] = sum_i Vp[c][i] * 2^(s[i,j])
__global__ __launch_bounds__(256, 2)
void attn_pv_kernel(const unsigned short* __restrict__ Kt,
                    const unsigned short* __restrict__ Qt,
                    const unsigned short* __restrict__ Vp,
                    unsigned short* __restrict__ AOt)
{
  // K only in LDS: 3 pair-slots x 2 tiles x 8 KB = 48 KB
  __shared__ __attribute__((aligned(16))) unsigned short Kbuf[3][2][64*64/ (64/64)][1];
  // (dimension trick avoided; flat layout below)
  __shared__ __attribute__((aligned(16))) unsigned short Kb[3][2][4096];

  const int m = blockIdx.x;                    // 512 blocks
  const int xcd = m & 7, slot = m >> 3;        // 64 slots per XCD
  const int bh = xcd * 8 + (slot >> 3);        // 8 bh per XCD
  const int jb = slot & 7;
  const int b = bh >> 4, h = bh & 15;
  const int j0 = jb * 256;

  const int tid = threadIdx.x, w = tid >> 6, lane = tid & 63;
  const int l31 = lane & 31, lh = lane >> 5;
  const int jw = j0 + w * 64;                  // wave owns 64 j-cols (2 sets of 32)

  bf16x8 qb[2][4];
  #pragma unroll
  for (int js = 0; js < 2; ++js)
    #pragma unroll
    for (int ks = 0; ks < 4; ++ks)
      qb[js][ks] = *(const bf16x8*)(Qt + ((size_t)b*Ld + jw + js*32 + l31)*Sd + h*64 + ks*16 + lh*8);

  float16v oacc[2][2];   // [ds][js]
  #pragma unroll
  for (int ds = 0; ds < 2; ++ds)
    #pragma unroll
    for (int js = 0; js < 2; ++js)
      #pragma unroll
      for (int r = 0; r < 16; ++r) oacc[ds][js][r] = 0.f;

  const size_t kbase = (size_t)b*Ld*Sd + (size_t)h*64;
  const size_t vbase = ((size_t)b*Sd + h*64)*Ld;

  // stage one K tile (64 i-rows x 64 d) into slot/half; 2 gload per thread
  auto stage_tile = [&](int sl, int hf, int it){
    const int i0 = it * 64;
    #pragma unroll
    for (int p = 0; p < 2; ++p){
      const int slot2 = p*256 + tid;
      const int row = slot2 >> 3;
      const int gsrc = (slot2 & 7) ^ (row & 7);
      gload_lds16(Kt + kbase + (size_t)(i0 + row)*Sd + gsrc*8,
                  (void*)(&Kb[sl][hf][(size_t)slot2 * 8]));
    }
  };
  auto stage_pair = [&](int p){   // tiles 2p, 2p+1 -> slot p%3
    stage_tile(p % 3, 0, 2*p);
    stage_tile(p % 3, 1, 2*p + 1);
  };

  bf16x8 kf[2][4], vf[2][4];
  float16v sacc2[2][2];  // [is][js]

  auto read_kf = [&](int u){   // tile u from LDS
    const int sl = (u >> 1) % 3, hf = u & 1;
    #pragma unroll
    for (int is = 0; is < 2; ++is)
      #pragma unroll
      for (int ks = 0; ks < 4; ++ks){
        const int row = is*32 + l31;
        const int g = (2*ks + lh) ^ (l31 & 7);
        kf[is][ks] = *(const bf16x8*)((const char*)&Kb[sl][hf][0] + (size_t)row*128 + g*16);
      }
  };
  auto read_vf = [&](int u){   // tile u direct from global (L2-resident)
    const int i0 = u * 64;
    #pragma unroll
    for (int is = 0; is < 2; ++is)
      #pragma unroll
      for (int ks = 0; ks < 4; ++ks){
        const int row = is*32 + l31;
        vf[is][ks] = *(const bf16x8*)(Vp + vbase + (size_t)row*Ld + i0 + (2*ks + lh)*8);
      }
  };
  auto do_qk = [&](){
    #pragma unroll
    for (int is = 0; is < 2; ++is)
      #pragma unroll
      for (int js = 0; js < 2; ++js)
        #pragma unroll
        for (int r = 0; r < 16; ++r) sacc2[is][js][r] = 0.f;
    __builtin_amdgcn_s_setprio(1);
    #pragma unroll
    for (int js = 0; js < 2; ++js)
      #pragma unroll
      for (int is = 0; is < 2; ++is)
        #pragma unroll
        for (int ks = 0; ks < 4; ++ks)
          sacc2[is][js] = mfma32_bf16(kf[is][ks], qb[js][ks], sacc2[is][js]);
    __builtin_amdgcn_s_setprio(0);
  };
  auto do_exp_pv = [&](){
    #pragma unroll
    for (int js = 0; js < 2; ++js){
      bf16x8 pf[4];
      #pragma unroll
      for (int is = 0; is < 2; ++is){
        #pragma unroll
        for (int hs = 0; hs < 2; ++hs){
          const int r0 = 8*hs;
          unsigned W0 = pack2(fast_exp2(sacc2[is][js][r0+0]), fast_exp2(sacc2[is][js][r0+1]));
          unsigned W1 = pack2(fast_exp2(sacc2[is][js][r0+2]), fast_exp2(sacc2[is][js][r0+3]));
          unsigned W2 = pack2(fast_exp2(sacc2[is][js][r0+4]), fast_exp2(sacc2[is][js][r0+5]));
          unsigned W3 = pack2(fast_exp2(sacc2[is][js][r0+6]), fast_exp2(sacc2[is][js][r0+7]));
          plane32_swap(W0, W2);
          plane32_swap(W1, W3);
          union { uint4v u; bf16x8 v; } cvt;
          cvt.u = (uint4v){ W0, W1, W2, W3 };
          pf[is*2 + hs] = cvt.v;
        }
      }
      __builtin_amdgcn_s_setprio(1);
      #pragma unroll
      for (int kp = 0; kp < 4; ++kp)
        #pragma unroll
        for (int ds = 0; ds < 2; ++ds)
          oacc[ds][js] = mfma32_bf16(vf[ds][kp], pf[kp], oacc[ds][js]);
      __builtin_amdgcn_s_setprio(0);
    }
  };

  // prologue: pairs 0,1 (tiles 0..3) staged; V tile 0 rolled in registers
  stage_pair(0);
  stage_pair(1);
  __syncthreads();        // tiles 0..3 landed
  read_kf(0);
  do_qk();                // sacc2 = QK(0)
  read_vf(0);

  // main pipeline: per-tile rolling regs; barrier + pair-stage every 2 tiles
  for (int t = 0; t < 31; ++t){
    if ((t & 1) == 0){
      if (t > 0) __syncthreads();          // pair t/2+1 landed; slot (t/2+2)%3 reads done
      if (t <= 26) stage_pair(t/2 + 2);    // tiles t+4, t+5
    }
    read_kf(t + 1);
    do_exp_pv();                           // exp/pack(t) + PV(t)
    do_qk();                               // QK(t+1)
    read_vf(t + 1);                        // V(t+1) direct global, lands during next body
  }
  do_exp_pv();                             // tail: tile 31

  #pragma unroll
  for (int ds = 0; ds < 2; ++ds)
    #pragma unroll
    for (int js = 0; js < 2; ++js)
      #pragma unroll
      for (int rq = 0; rq < 4; ++rq){
        const int d0 = ds*32 + 8*rq + 4*lh;
        ushort4v o = { f2bf(oacc[ds][js][4*rq+0]), f2bf(oacc[ds][js][4*rq+1]),
                       f2bf(oacc[ds][js][4*rq+2]), f2bf(oacc[ds][js][4*rq+3]) };
        *(ushort4v*)(AOt + ((size_t)b*Ld + jw + js*32 + l31)*Sd + h*64 + d0) = o;
      }
  (void)Kbuf;
}

// ---------------- launch ----------------

extern "C" void kernel_launch(void* const* d_in, const int* in_sizes, int n_in,
                              void* d_out, int out_size, void* d_ws, size_t ws_size,
                              hipStream_t stream)
{
  const float* x  = (const float*)d_in[0];
  const float* Wk = (const float*)d_in[1];
  const float* bk = (const float*)d_in[2];
  const float* Wq = (const float*)d_in[3];
  const float* bq = (const float*)d_in[4];
  const float* Wp = (const float*)d_in[5];
  const float* bp = (const float*)d_in[6];
  float* out = (float*)d_out;

  char* ws = (char*)d_ws;
  const size_t SZ_BLS = (size_t)Bd * Ld * Sd * 2;   // 16 MB
  unsigned short* Xt   = (unsigned short*)(ws);
  unsigned short* Kt   = (unsigned short*)(ws + SZ_BLS);
  unsigned short* Qt   = (unsigned short*)(ws + 2*SZ_BLS);
  unsigned short* AOt  = (unsigned short*)(ws + 3*SZ_BLS);
  unsigned short* Wkbf = (unsigned short*)(ws + 4*SZ_BLS);
  unsigned short* Wqbf = (unsigned short*)(ws + 4*SZ_BLS + (size_t)2097152);
  unsigned short* Wpbf = (unsigned short*)(ws + 4*SZ_BLS + (size_t)2*2097152);
  unsigned short* Vp   = Xt;  // alias: Xt is dead after the KQ conv

  const float ck = (2.0f / (float)Ld) * 1.44269504088896f;

  wcast_kernel<<<1024, 256, 0, stream>>>(Wk, Wq, Wp, Wkbf, Wqbf, Wpbf, ck);
  transpose_cast<<<dim3(Ld/32, Sd/32, Bd), 256, 0, stream>>>(x, Xt);

  dim3 cg(Ld/128, Sd/128, Bd);
  conv_gemm_kq<<<cg, 256, 0, stream>>>(Wkbf, Wqbf, Xt, bk, bq, ck, Kt, Qt);

  stats_kernel<<<dim3((Ld/256)*(Bd*Hd)), 256, 0, stream>>>(Kt, Qt, x, Vp);
  attn_pv_kernel<<<dim3((Ld/256)*(Bd*Hd)), 256, 0, stream>>>(Kt, Qt, Vp, AOt);

  conv_gemm<1><<<cg, 256, 0, stream>>>(Wpbf, AOt, bp, 1.0f, nullptr, out);
}

// Round 12
// 214.509 us; speedup vs baseline: 2.6396x; 2.6396x over previous
//
#include <hip/hip_runtime.h>
#include <hip/hip_bf16.h>
#include <cstdint>
#include <cstddef>

#ifndef __has_builtin
#define __has_builtin(x) 0
#endif

#define DEVI __device__ __forceinline__

typedef __attribute__((ext_vector_type(8))) __bf16 bf16x8;
typedef __attribute__((ext_vector_type(4))) float float4v;
typedef __attribute__((ext_vector_type(16))) float float16v;
typedef __attribute__((ext_vector_type(4))) unsigned short ushort4v;
typedef __attribute__((ext_vector_type(4))) unsigned int uint4v;

constexpr int Bd = 4, Sd = 1024, Ld = 2048, Hd = 16, Dd = 64;

DEVI unsigned short f2bf(float x){
  union { float f; unsigned u; } v; v.f = x;
  unsigned r = v.u + 0x7fffu + ((v.u >> 16) & 1u);
  return (unsigned short)(r >> 16);
}

// Half-up pack two f32 -> u32 of 2 bf16 (lo | hi<<16). 3 VALU ops.
DEVI unsigned pack2(float lo, float hi){
  union { float f; unsigned u; } a, b; a.f = lo; b.f = hi;
  unsigned ra = a.u + 0x8000u;
  unsigned rb = b.u + 0x8000u;
#if __has_builtin(__builtin_amdgcn_perm)
  return __builtin_amdgcn_perm(rb, ra, 0x07060302u);  // D = [rb.hi16 | ra.hi16]
#else
  return (ra >> 16) | (rb & 0xffff0000u);
#endif
}

DEVI float fast_exp2(float x){
#if __has_builtin(__builtin_amdgcn_exp2f)
  return __builtin_amdgcn_exp2f(x);
#else
  return exp2f(x);
#endif
}

// v_permlane32_swap_b32 D,S: new_D=[D.lo|S.lo], new_S=[D.hi|S.hi] (lane halves).
DEVI void plane32_swap(unsigned &a, unsigned &b){
  asm("v_permlane32_swap_b32 %0, %1" : "+v"(a), "+v"(b));
}

DEVI void gload_lds16(const void* g, void* lds){
  __builtin_amdgcn_global_load_lds(
      (const __attribute__((address_space(1))) void*)g,
      (__attribute__((address_space(3))) void*)lds,
      16, 0, 0);
}

DEVI float4v mfma_bf16(bf16x8 a, bf16x8 b, float4v c){
  return __builtin_amdgcn_mfma_f32_16x16x32_bf16(a, b, c, 0, 0, 0);
}

DEVI float16v mfma32_bf16(bf16x8 a, bf16x8 b, float16v c){
  return __builtin_amdgcn_mfma_f32_32x32x16_bf16(a, b, c, 0, 0, 0);
}

// ---------------- prep kernels ----------------

__global__ void wcast_kernel(const float* __restrict__ Wk, const float* __restrict__ Wq,
                             const float* __restrict__ Wp,
                             unsigned short* __restrict__ Wkbf, unsigned short* __restrict__ Wqbf,
                             unsigned short* __restrict__ Wpbf, float ck){
  size_t i = ((size_t)blockIdx.x * 256 + threadIdx.x) * 4;
  float4v a = *(const float4v*)(Wk + i);
  float4v b = *(const float4v*)(Wq + i);
  float4v c = *(const float4v*)(Wp + i);
  ushort4v oa = { f2bf(a[0]*ck), f2bf(a[1]*ck), f2bf(a[2]*ck), f2bf(a[3]*ck) };
  ushort4v ob = { f2bf(b[0]), f2bf(b[1]), f2bf(b[2]), f2bf(b[3]) };
  ushort4v oc = { f2bf(c[0]), f2bf(c[1]), f2bf(c[2]), f2bf(c[3]) };
  *(ushort4v*)(Wkbf + i) = oa;
  *(ushort4v*)(Wqbf + i) = ob;
  *(ushort4v*)(Wpbf + i) = oc;
}

// x (B,S,L) f32 -> Xt (B,L,S) bf16. float4 loads, ushort4 stores.
__global__ void transpose_cast(const float* __restrict__ x, unsigned short* __restrict__ Xt){
  __shared__ float tile[32][33];
  const int b = blockIdx.z;
  const int l0 = blockIdx.x * 32;
  const int s0 = blockIdx.y * 32;
  const int t = threadIdx.x;           // 256 threads
  {
    const int r = t >> 3, c4 = (t & 7) * 4;   // s-row r, l-col group c4
    float4v v = *(const float4v*)(x + ((size_t)b*Sd + s0 + r)*Ld + l0 + c4);
    tile[r][c4+0] = v[0]; tile[r][c4+1] = v[1];
    tile[r][c4+2] = v[2]; tile[r][c4+3] = v[3];
  }
  __syncthreads();
  {
    const int l = t >> 3, g4 = (t & 7) * 4;   // l-row, s-col group
    ushort4v o = { f2bf(tile[g4+0][l]), f2bf(tile[g4+1][l]),
                   f2bf(tile[g4+2][l]), f2bf(tile[g4+3][l]) };
    *(ushort4v*)(Xt + ((size_t)b*Ld + l0 + l)*Sd + s0 + g4) = o;
  }
}

// ---------------- conv1x1 GEMM (128x128 tile, BK=32, dbuf, global_load_lds) ----------------
template<int OUT_MODE>
__global__ __launch_bounds__(256, 2)
void conv_gemm(const unsigned short* __restrict__ A,
               const unsigned short* __restrict__ Bt,
               const float* __restrict__ bias, float bscale,
               unsigned short* __restrict__ outT,
               float* __restrict__ outF)
{
  constexpr int BK = 32;
  constexpr int NKSTEP = Sd / BK;  // 32
  __shared__ __attribute__((aligned(16))) unsigned short Abuf[2][128*BK];
  __shared__ __attribute__((aligned(16))) unsigned short Bbuf[2][128*BK];

  const int b  = blockIdx.z;
  const int n0 = blockIdx.x * 128;
  const int m0 = blockIdx.y * 128;
  const int tid = threadIdx.x;
  const int w = tid >> 6, lane = tid & 63, lr = lane & 15, lg = lane >> 4;
  const int wm = (w >> 1) * 64, wn = (w & 1) * 64;

  const unsigned short* Abase = A + (size_t)m0 * Sd;
  const unsigned short* Bbase = Bt + ((size_t)b * Ld + n0) * Sd;

  auto stage = [&](int bf, int kt){
    #pragma unroll
    for (int p = 0; p < 2; ++p){
      int slot = p*256 + tid;
      int row = slot >> 2, c = slot & 3;
      int csrc = c ^ ((row >> 1) & 3);
      gload_lds16(Abase + (size_t)row * Sd + kt*BK + csrc*8,
                  (void*)(&Abuf[bf][(size_t)(p*256 + w*64) * 8]));
    }
    #pragma unroll
    for (int p = 0; p < 2; ++p){
      int slot = p*256 + tid;
      int row = slot >> 2, c = slot & 3;
      int csrc = c ^ ((row >> 1) & 3);
      gload_lds16(Bbase + (size_t)row * Sd + kt*BK + csrc*8,
                  (void*)(&Bbuf[bf][(size_t)(p*256 + w*64) * 8]));
    }
  };

  const int gsw = lg ^ ((lr >> 1) & 3);

  float4v acc[4][4];
  #pragma unroll
  for (int i = 0; i < 4; ++i)
    #pragma unroll
    for (int j = 0; j < 4; ++j)
      acc[i][j] = (float4v){0.f, 0.f, 0.f, 0.f};

  stage(0, 0);
  __syncthreads();
  int cur = 0;
  for (int kt = 0; kt < NKSTEP; ++kt){
    if (kt + 1 < NKSTEP) stage(cur ^ 1, kt + 1);
    bf16x8 af[4], bfv[4];
    #pragma unroll
    for (int i = 0; i < 4; ++i){
      int row = wm + i*16 + lr;
      af[i] = *(const bf16x8*)((const char*)&Abuf[cur][0] + (size_t)row*64 + gsw*16);
    }
    #pragma unroll
    for (int j = 0; j < 4; ++j){
      int row = wn + j*16 + lr;
      bfv[j] = *(const bf16x8*)((const char*)&Bbuf[cur][0] + (size_t)row*64 + gsw*16);
    }
    #pragma unroll
    for (int i = 0; i < 4; ++i)
      #pragma unroll
      for (int j = 0; j < 4; ++j)
        acc[i][j] = mfma_bf16(af[i], bfv[j], acc[i][j]);
    __syncthreads();
    cur ^= 1;
  }

  #pragma unroll
  for (int i = 0; i < 4; ++i){
    const int mb = m0 + wm + i*16 + lg*4;
    float4v bv = *(const float4v*)(bias + mb);
    #pragma unroll
    for (int j = 0; j < 4; ++j){
      const int n = n0 + wn + j*16 + lr;
      float4v v = acc[i][j];
      float o0 = v[0] + bscale*bv[0];
      float o1 = v[1] + bscale*bv[1];
      float o2 = v[2] + bscale*bv[2];
      float o3 = v[3] + bscale*bv[3];
      if (OUT_MODE == 0){
        ushort4v o = { f2bf(o0), f2bf(o1), f2bf(o2), f2bf(o3) };
        *(ushort4v*)(outT + ((size_t)b*Ld + n)*Sd + mb) = o;
      } else {
        outF[((size_t)b*Sd + mb + 0)*Ld + n] = o0;
        outF[((size_t)b*Sd + mb + 1)*Ld + n] = o1;
        outF[((size_t)b*Sd + mb + 2)*Ld + n] = o2;
        outF[((size_t)b*Sd + mb + 3)*Ld + n] = o3;
      }
    }
  }
}

// ---------------- fused K+Q conv: both GEMMs share the Xt B-operand ----------------
__global__ __launch_bounds__(256, 2)
void conv_gemm_kq(const unsigned short* __restrict__ Ak,
                  const unsigned short* __restrict__ Aq,
                  const unsigned short* __restrict__ Bt,
                  const float* __restrict__ bk, const float* __restrict__ bq,
                  float ck,
                  unsigned short* __restrict__ Kt,
                  unsigned short* __restrict__ Qt)
{
  constexpr int BK = 32;
  constexpr int NKSTEP = Sd / BK;  // 32
  __shared__ __attribute__((aligned(16))) unsigned short AbufK[2][128*BK];
  __shared__ __attribute__((aligned(16))) unsigned short AbufQ[2][128*BK];
  __shared__ __attribute__((aligned(16))) unsigned short Bbuf[2][128*BK];   // 48 KB total

  const int b  = blockIdx.z;
  const int n0 = blockIdx.x * 128;
  const int m0 = blockIdx.y * 128;
  const int tid = threadIdx.x;
  const int w = tid >> 6, lane = tid & 63, lr = lane & 15, lg = lane >> 4;
  const int wm = (w >> 1) * 64, wn = (w & 1) * 64;

  const unsigned short* AKbase = Ak + (size_t)m0 * Sd;
  const unsigned short* AQbase = Aq + (size_t)m0 * Sd;
  const unsigned short* Bbase  = Bt + ((size_t)b * Ld + n0) * Sd;

  auto stage = [&](int bf, int kt){
    #pragma unroll
    for (int p = 0; p < 2; ++p){
      int slot = p*256 + tid;
      int row = slot >> 2, c = slot & 3;
      int csrc = c ^ ((row >> 1) & 3);
      const size_t soff = (size_t)row * Sd + kt*BK + csrc*8;
      void* dk = (void*)(&AbufK[bf][(size_t)(p*256 + w*64) * 8]);
      void* dq = (void*)(&AbufQ[bf][(size_t)(p*256 + w*64) * 8]);
      void* db = (void*)(&Bbuf [bf][(size_t)(p*256 + w*64) * 8]);
      gload_lds16(AKbase + soff, dk);
      gload_lds16(AQbase + soff, dq);
      gload_lds16(Bbase  + soff, db);
    }
  };

  const int gsw = lg ^ ((lr >> 1) & 3);

  float4v acck[4][4], accq[4][4];
  #pragma unroll
  for (int i = 0; i < 4; ++i)
    #pragma unroll
    for (int j = 0; j < 4; ++j){
      acck[i][j] = (float4v){0.f, 0.f, 0.f, 0.f};
      accq[i][j] = (float4v){0.f, 0.f, 0.f, 0.f};
    }

  stage(0, 0);
  __syncthreads();
  int cur = 0;
  for (int kt = 0; kt < NKSTEP; ++kt){
    if (kt + 1 < NKSTEP) stage(cur ^ 1, kt + 1);
    bf16x8 afk[4], afq[4], bfv[4];
    #pragma unroll
    for (int i = 0; i < 4; ++i){
      int row = wm + i*16 + lr;
      afk[i] = *(const bf16x8*)((const char*)&AbufK[cur][0] + (size_t)row*64 + gsw*16);
      afq[i] = *(const bf16x8*)((const char*)&AbufQ[cur][0] + (size_t)row*64 + gsw*16);
    }
    #pragma unroll
    for (int j = 0; j < 4; ++j){
      int row = wn + j*16 + lr;
      bfv[j] = *(const bf16x8*)((const char*)&Bbuf[cur][0] + (size_t)row*64 + gsw*16);
    }
    #pragma unroll
    for (int i = 0; i < 4; ++i)
      #pragma unroll
      for (int j = 0; j < 4; ++j){
        acck[i][j] = mfma_bf16(afk[i], bfv[j], acck[i][j]);
        accq[i][j] = mfma_bf16(afq[i], bfv[j], accq[i][j]);
      }
    __syncthreads();
    cur ^= 1;
  }

  #pragma unroll
  for (int i = 0; i < 4; ++i){
    const int mb = m0 + wm + i*16 + lg*4;
    float4v bkv = *(const float4v*)(bk + mb);
    float4v bqv = *(const float4v*)(bq + mb);
    #pragma unroll
    for (int j = 0; j < 4; ++j){
      const int n = n0 + wn + j*16 + lr;
      float4v vk = acck[i][j];
      float4v vq = accq[i][j];
      ushort4v ok = { f2bf(vk[0] + ck*bkv[0]), f2bf(vk[1] + ck*bkv[1]),
                      f2bf(vk[2] + ck*bkv[2]), f2bf(vk[3] + ck*bkv[3]) };
      ushort4v oq = { f2bf(vq[0] + bqv[0]), f2bf(vq[1] + bqv[1]),
                      f2bf(vq[2] + bqv[2]), f2bf(vq[3] + bqv[3]) };
      *(ushort4v*)(Kt + ((size_t)b*Ld + n)*Sd + mb) = ok;
      *(ushort4v*)(Qt + ((size_t)b*Ld + n)*Sd + mb) = oq;
    }
  }
}

// ---------------- stats v4 (i-split 2x) + fused vprime ----------------
// invZ for i-range 128 per block; grid 1024 -> 4 blocks/CU target.
__global__ __launch_bounds__(256, 4)
void stats_kernel(const unsigned short* __restrict__ Kt,
                  const unsigned short* __restrict__ Qt,
                  const float* __restrict__ x,
                  unsigned short* __restrict__ Vp)
{
  __shared__ __attribute__((aligned(16))) unsigned short Qbuf[2][64*64];  // 16 KB
  __shared__ __attribute__((aligned(16))) float zbuf[128];                // 512 B

  const int m = blockIdx.x;                    // 1024 blocks
  const int xcd = m & 7, slot = m >> 3;        // 128 slots per XCD
  const int bh = xcd * 8 + (slot >> 4);        // 8 bh per XCD
  const int ib = slot & 15;
  const int b = bh >> 4, h = bh & 15;
  const int i0 = ib * 128;

  const int tid = threadIdx.x, w = tid >> 6, lane = tid & 63;
  const int l31 = lane & 31, lh = lane >> 5;
  const int iw0 = i0 + w * 32;                 // wave owns 32 i-cols

  // K fragments (loop-invariant): col i = iw0 + l31
  bf16x8 kb[4];
  #pragma unroll
  for (int ks = 0; ks < 4; ++ks)
    kb[ks] = *(const bf16x8*)(Kt + ((size_t)b*Ld + iw0 + l31)*Sd + h*64 + ks*16 + lh*8);

  const size_t qbase = (size_t)b*Ld*Sd + (size_t)h*64;
  auto stage = [&](int bf, int jt){
    const int j0 = jt * 64;
    #pragma unroll
    for (int p = 0; p < 2; ++p){
      const int slot2 = p*256 + tid;
      const int row = slot2 >> 3;
      const int gsrc = (slot2 & 7) ^ (row & 7);
      gload_lds16(Qt + qbase + (size_t)(j0 + row)*Sd + gsrc*8,
                  (void*)(&Qbuf[bf][(size_t)slot2 * 8]));
    }
  };

  float z = 0.f;
  stage(0, 0);
  __syncthreads();
  int cur = 0;
  for (int jt = 0; jt < 32; ++jt){
    if (jt + 1 < 32) stage(cur ^ 1, jt + 1);
    #pragma unroll
    for (int js = 0; js < 2; ++js){
      bf16x8 qf[4];
      #pragma unroll
      for (int ks = 0; ks < 4; ++ks){
        const int row = js*32 + l31;
        const int g = (2*ks + lh) ^ (l31 & 7);
        qf[ks] = *(const bf16x8*)((const char*)&Qbuf[cur][0] + (size_t)row*128 + g*16);
      }
      float16v sacc;
      #pragma unroll
      for (int r = 0; r < 16; ++r) sacc[r] = 0.f;
      __builtin_amdgcn_s_setprio(1);
      #pragma unroll
      for (int ks = 0; ks < 4; ++ks)
        sacc = mfma32_bf16(qf[ks], kb[ks], sacc);   // D[row=j][col=i]
      __builtin_amdgcn_s_setprio(0);
      #pragma unroll
      for (int r = 0; r < 16; ++r) z += fast_exp2(sacc[r]);
    }
    __syncthreads();
    cur ^= 1;
  }

  // invZ for this block's 128 i -> LDS
  {
    float zv = z + __shfl_xor(z, 32, 64);   // combine lh halves (disjoint j)
    if (lh == 0)
      zbuf[w*32 + l31] = 1.0f / zv;
  }
  __syncthreads();

  // fused vprime: Vp[b][h*64+d][i0..i0+127] = bf16(x * invZ), 8 float4 per thread
  #pragma unroll
  for (int p = 0; p < 8; ++p){
    const int e = p*256 + tid;          // 2048 float4 groups
    const int d = e >> 5;               // 0..63
    const int c4 = (e & 31) * 4;        // i offset 0..124
    const size_t off = ((size_t)b*Sd + h*64 + d)*Ld + i0 + c4;
    float4v xv = *(const float4v*)(x + off);
    float4v zv = *(const float4v*)(&zbuf[c4]);
    ushort4v o = { f2bf(xv[0]*zv[0]), f2bf(xv[1]*zv[1]),
                   f2bf(xv[2]*zv[2]), f2bf(xv[3]*zv[3]) };
    *(ushort4v*)(Vp + off) = o;
  }
}

// ---------------- PV pass (round-10 proven): cross-iter SW pipeline, j_wave=64 ----------
// AOt[b][j][c] = sum_i Vp[c][i] * 2^(s[i,j])
__global__ __launch_bounds__(256, 2)
void attn_pv_kernel(const unsigned short* __restrict__ Kt,
                    const unsigned short* __restrict__ Qt,
                    const unsigned short* __restrict__ Vp,
                    unsigned short* __restrict__ AOt)
{
  __shared__ __attribute__((aligned(16))) unsigned short Kbuf[2][64*64];  // 16 KB
  __shared__ __attribute__((aligned(16))) unsigned short Vbuf[2][64*64];  // 16 KB

  const int m = blockIdx.x;                    // 512 blocks
  const int xcd = m & 7, slot = m >> 3;        // 64 slots per XCD
  const int bh = xcd * 8 + (slot >> 3);        // 8 bh per XCD
  const int jb = slot & 7;
  const int b = bh >> 4, h = bh & 15;
  const int j0 = jb * 256;

  const int tid = threadIdx.x, w = tid >> 6, lane = tid & 63;
  const int l31 = lane & 31, lh = lane >> 5;
  const int jw = j0 + w * 64;                  // wave owns 64 j-cols (2 sets of 32)

  bf16x8 qb[2][4];
  #pragma unroll
  for (int js = 0; js < 2; ++js)
    #pragma unroll
    for (int ks = 0; ks < 4; ++ks)
      qb[js][ks] = *(const bf16x8*)(Qt + ((size_t)b*Ld + jw + js*32 + l31)*Sd + h*64 + ks*16 + lh*8);

  float16v oacc[2][2];   // [ds][js]
  #pragma unroll
  for (int ds = 0; ds < 2; ++ds)
    #pragma unroll
    for (int js = 0; js < 2; ++js)
      #pragma unroll
      for (int r = 0; r < 16; ++r) oacc[ds][js][r] = 0.f;

  const size_t kbase = (size_t)b*Ld*Sd + (size_t)h*64;
  const size_t vbase = ((size_t)b*Sd + h*64)*Ld;

  auto stage = [&](int bf, int it){
    const int i0 = it * 64;
    #pragma unroll
    for (int p = 0; p < 2; ++p){
      const int slot2 = p*256 + tid;
      const int row = slot2 >> 3;
      const int gsrc = (slot2 & 7) ^ (row & 7);
      gload_lds16(Kt + kbase + (size_t)(i0 + row)*Sd + gsrc*8,
                  (void*)(&Kbuf[bf][(size_t)slot2 * 8]));
      gload_lds16(Vp + vbase + (size_t)row*Ld + i0 + gsrc*8,
                  (void*)(&Vbuf[bf][(size_t)slot2 * 8]));
    }
  };

  bf16x8 kf[2][4], vf[2][4];
  float16v sacc2[2][2];  // [is][js]

  auto read_kf = [&](int cb){
    #pragma unroll
    for (int is = 0; is < 2; ++is)
      #pragma unroll
      for (int ks = 0; ks < 4; ++ks){
        const int row = is*32 + l31;
        const int g = (2*ks + lh) ^ (l31 & 7);
        kf[is][ks] = *(const bf16x8*)((const char*)&Kbuf[cb][0] + (size_t)row*128 + g*16);
      }
  };
  auto read_vf = [&](int cb){
    #pragma unroll
    for (int is = 0; is < 2; ++is)
      #pragma unroll
      for (int ks = 0; ks < 4; ++ks){
        const int row = is*32 + l31;
        const int g = (2*ks + lh) ^ (l31 & 7);
        vf[is][ks] = *(const bf16x8*)((const char*)&Vbuf[cb][0] + (size_t)row*128 + g*16);
      }
  };
  auto do_qk = [&](){
    #pragma unroll
    for (int is = 0; is < 2; ++is)
      #pragma unroll
      for (int js = 0; js < 2; ++js)
        #pragma unroll
        for (int r = 0; r < 16; ++r) sacc2[is][js][r] = 0.f;
    __builtin_amdgcn_s_setprio(1);
    #pragma unroll
    for (int js = 0; js < 2; ++js)
      #pragma unroll
      for (int is = 0; is < 2; ++is)
        #pragma unroll
        for (int ks = 0; ks < 4; ++ks)
          sacc2[is][js] = mfma32_bf16(kf[is][ks], qb[js][ks], sacc2[is][js]);
    __builtin_amdgcn_s_setprio(0);
  };
  auto do_exp_pv = [&](){
    #pragma unroll
    for (int js = 0; js < 2; ++js){
      bf16x8 pf[4];
      #pragma unroll
      for (int is = 0; is < 2; ++is){
        #pragma unroll
        for (int hs = 0; hs < 2; ++hs){
          const int r0 = 8*hs;
          unsigned W0 = pack2(fast_exp2(sacc2[is][js][r0+0]), fast_exp2(sacc2[is][js][r0+1]));
          unsigned W1 = pack2(fast_exp2(sacc2[is][js][r0+2]), fast_exp2(sacc2[is][js][r0+3]));
          unsigned W2 = pack2(fast_exp2(sacc2[is][js][r0+4]), fast_exp2(sacc2[is][js][r0+5]));
          unsigned W3 = pack2(fast_exp2(sacc2[is][js][r0+6]), fast_exp2(sacc2[is][js][r0+7]));
          plane32_swap(W0, W2);
          plane32_swap(W1, W3);
          union { uint4v u; bf16x8 v; } cvt;
          cvt.u = (uint4v){ W0, W1, W2, W3 };
          pf[is*2 + hs] = cvt.v;
        }
      }
      __builtin_amdgcn_s_setprio(1);
      #pragma unroll
      for (int kp = 0; kp < 4; ++kp)
        #pragma unroll
        for (int ds = 0; ds < 2; ++ds)
          oacc[ds][js] = mfma32_bf16(vf[ds][kp], pf[kp], oacc[ds][js]);
      __builtin_amdgcn_s_setprio(0);
    }
  };

  // prologue
  stage(0, 0);
  __syncthreads();        // tile 0 landed
  stage(1, 1);            // tile 1 in flight
  read_kf(0);
  do_qk();                // sacc2 = QK(0)
  read_vf(0);

  // main pipeline: body(t) finishes tile t, starts tile t+1
  for (int t = 0; t < 31; ++t){
    __syncthreads();                       // tile t+1 landed; tile-t reads all done
    if (t < 30) stage(t & 1, t + 2);       // overwrite dead buf with tile t+2
    read_kf((t + 1) & 1);
    do_exp_pv();                           // exp/pack(t) + PV(t)
    do_qk();                               // QK(t+1)
    read_vf((t + 1) & 1);
  }
  do_exp_pv();                             // tail: tile 31

  #pragma unroll
  for (int ds = 0; ds < 2; ++ds)
    #pragma unroll
    for (int js = 0; js < 2; ++js)
      #pragma unroll
      for (int rq = 0; rq < 4; ++rq){
        const int d0 = ds*32 + 8*rq + 4*lh;
        ushort4v o = { f2bf(oacc[ds][js][4*rq+0]), f2bf(oacc[ds][js][4*rq+1]),
                       f2bf(oacc[ds][js][4*rq+2]), f2bf(oacc[ds][js][4*rq+3]) };
        *(ushort4v*)(AOt + ((size_t)b*Ld + jw + js*32 + l31)*Sd + h*64 + d0) = o;
      }
}

// ---------------- launch ----------------

extern "C" void kernel_launch(void* const* d_in, const int* in_sizes, int n_in,
                              void* d_out, int out_size, void* d_ws, size_t ws_size,
                              hipStream_t stream)
{
  const float* x  = (const float*)d_in[0];
  const float* Wk = (const float*)d_in[1];
  const float* bk = (const float*)d_in[2];
  const float* Wq = (const float*)d_in[3];
  const float* bq = (const float*)d_in[4];
  const float* Wp = (const float*)d_in[5];
  const float* bp = (const float*)d_in[6];
  float* out = (float*)d_out;

  char* ws = (char*)d_ws;
  const size_t SZ_BLS = (size_t)Bd * Ld * Sd * 2;   // 16 MB
  unsigned short* Xt   = (unsigned short*)(ws);
  unsigned short* Kt   = (unsigned short*)(ws + SZ_BLS);
  unsigned short* Qt   = (unsigned short*)(ws + 2*SZ_BLS);
  unsigned short* AOt  = (unsigned short*)(ws + 3*SZ_BLS);
  unsigned short* Wkbf = (unsigned short*)(ws + 4*SZ_BLS);
  unsigned short* Wqbf = (unsigned short*)(ws + 4*SZ_BLS + (size_t)2097152);
  unsigned short* Wpbf = (unsigned short*)(ws + 4*SZ_BLS + (size_t)2*2097152);
  unsigned short* Vp   = Xt;  // alias: Xt is dead after the KQ conv

  const float ck = (2.0f / (float)Ld) * 1.44269504088896f;

  wcast_kernel<<<1024, 256, 0, stream>>>(Wk, Wq, Wp, Wkbf, Wqbf, Wpbf, ck);
  transpose_cast<<<dim3(Ld/32, Sd/32, Bd), 256, 0, stream>>>(x, Xt);

  dim3 cg(Ld/128, Sd/128, Bd);
  conv_gemm_kq<<<cg, 256, 0, stream>>>(Wkbf, Wqbf, Xt, bk, bq, ck, Kt, Qt);

  stats_kernel<<<dim3((Ld/128)*(Bd*Hd)), 256, 0, stream>>>(Kt, Qt, x, Vp);
  attn_pv_kernel<<<dim3((Ld/256)*(Bd*Hd)), 256, 0, stream>>>(Kt, Qt, Vp, AOt);

  conv_gemm<1><<<cg, 256, 0, stream>>>(Wpbf, AOt, bp, 1.0f, nullptr, out);
}